// Round 1
// baseline (1210.834 us; speedup 1.0000x reference)
//
#include <hip/hip_runtime.h>
#include <hip/hip_bf16.h>
#include <cstdint>

// ---------------------------------------------------------------------------
// Model: 4x [LN -> QKV -> self-attn -> proj+res -> LN -> cross-attn ->
//            proj+res -> LN -> FC+GELU -> proj+res]
// B=2 T=2048 S=512 W=512 H=8 ch=64, all matmuls bf16 MFMA 16x16x32, fp32 accum.
// ---------------------------------------------------------------------------

typedef __bf16 bf16;
typedef __bf16 bf16x8 __attribute__((ext_vector_type(8)));
typedef float f32x4 __attribute__((ext_vector_type(4)));

#define AS1(p) ((__attribute__((address_space(1))) void*)(uintptr_t)(p))
#define AS3(p) ((__attribute__((address_space(3))) void*)(p))

#if defined(__has_builtin)
#if __has_builtin(__builtin_amdgcn_global_load_lds)
#define HAS_GLL 1
#endif
#endif
#ifndef HAS_GLL
#define HAS_GLL 0
#endif

__device__ __forceinline__ bf16 us2bf(unsigned short u) {
    return __builtin_bit_cast(bf16, u);
}

// ---------------- LayerNorm (f32 in) -> bf16 out, W=512 -------------------
__global__ __launch_bounds__(256) void ln_kernel(const float* __restrict__ x,
                                                 const float* __restrict__ gam,
                                                 const float* __restrict__ bet,
                                                 bf16* __restrict__ h) {
    int row  = blockIdx.x * 4 + (threadIdx.x >> 6);
    int lane = threadIdx.x & 63;
    const float4* xr = (const float4*)(x + (size_t)row * 512) + lane * 2;
    float4 a = xr[0], b = xr[1];
    float s  = a.x + a.y + a.z + a.w + b.x + b.y + b.z + b.w;
    float ss = a.x * a.x + a.y * a.y + a.z * a.z + a.w * a.w +
               b.x * b.x + b.y * b.y + b.z * b.z + b.w * b.w;
#pragma unroll
    for (int off = 1; off < 64; off <<= 1) {
        s  += __shfl_xor(s, off);
        ss += __shfl_xor(ss, off);
    }
    float mean = s * (1.f / 512.f);
    float var  = ss * (1.f / 512.f) - mean * mean;
    float rstd = rsqrtf(fmaxf(var, 0.f) + 1e-5f);
    const float4* gr = (const float4*)gam + lane * 2;
    const float4* br = (const float4*)bet + lane * 2;
    float4 g0 = gr[0], g1 = gr[1], b0 = br[0], b1 = br[1];
    bf16x8 hv;
    hv[0] = (bf16)((a.x - mean) * rstd * g0.x + b0.x);
    hv[1] = (bf16)((a.y - mean) * rstd * g0.y + b0.y);
    hv[2] = (bf16)((a.z - mean) * rstd * g0.z + b0.z);
    hv[3] = (bf16)((a.w - mean) * rstd * g0.w + b0.w);
    hv[4] = (bf16)((b.x - mean) * rstd * g1.x + b1.x);
    hv[5] = (bf16)((b.y - mean) * rstd * g1.y + b1.y);
    hv[6] = (bf16)((b.z - mean) * rstd * g1.z + b1.z);
    hv[7] = (bf16)((b.w - mean) * rstd * g1.w + b1.w);
    *(bf16x8*)(h + (size_t)row * 512 + lane * 8) = hv;
}

// ------------- transpose+convert: in f32 [L][K][N] -> out bf16 [L][N][K] ---
__global__ void wtrans_kernel(const float* __restrict__ in, bf16* __restrict__ out,
                              int K, int N) {
    __shared__ float tile[32][33];
    int n0 = blockIdx.x * 32, k0 = blockIdx.y * 32;
    const float* ip = in + (size_t)blockIdx.z * K * N;
    bf16* op = out + (size_t)blockIdx.z * N * K;
#pragma unroll
    for (int i = threadIdx.y; i < 32; i += 8)
        tile[i][threadIdx.x] = ip[(size_t)(k0 + i) * N + n0 + threadIdx.x];
    __syncthreads();
#pragma unroll
    for (int i = threadIdx.y; i < 32; i += 8)
        op[(size_t)(n0 + i) * K + k0 + threadIdx.x] = (bf16)tile[threadIdx.x][i];
}

// ------------- elementwise f32 -> bf16 ------------------------------------
__global__ void cvt_kernel(const float* __restrict__ in, bf16* __restrict__ out, int n) {
    int i = (blockIdx.x * 256 + threadIdx.x) * 8;
    if (i + 8 <= n) {
        const float4* p = (const float4*)(in + i);
        float4 a = p[0], b = p[1];
        bf16x8 v;
        v[0] = (bf16)a.x; v[1] = (bf16)a.y; v[2] = (bf16)a.z; v[3] = (bf16)a.w;
        v[4] = (bf16)b.x; v[5] = (bf16)b.y; v[6] = (bf16)b.z; v[7] = (bf16)b.w;
        *(bf16x8*)(out + i) = v;
    }
}

// ------------- GEMM: C = A[M][K] @ Bt[N][K]^T + bias, 128x128 tile ---------
// EPI 0: out bf16 = acc+bias
// EPI 1: out bf16 = gelu(acc+bias)
// EPI 2: out f32  = res + acc + bias     (res/out may alias: in-place x)
template <int EPI>
__global__ __launch_bounds__(256) void gemm_kernel(const bf16* __restrict__ A,
                                                   const bf16* __restrict__ Bt,
                                                   const float* __restrict__ bias,
                                                   const float* res, void* out,
                                                   int M, int N, int K) {
    __shared__ __align__(16) bf16 As[128 * 64];
    __shared__ __align__(16) bf16 Bs[128 * 64];
    int tiles_n = N >> 7;
    int bm = blockIdx.x / tiles_n, bn = blockIdx.x % tiles_n;
    int tid = threadIdx.x, wave = tid >> 6, lane = tid & 63;
    int wm = wave >> 1, wn = wave & 1;
    int g = lane >> 4, cc = lane & 15;
    f32x4 acc[4][4] = {};
    const bf16* Ag = A + (size_t)(bm << 7) * K;
    const bf16* Bg = Bt + (size_t)(bn << 7) * K;
    int srow = lane >> 3;        // 0..7 row within 8-row chunk
    int scol = (lane & 7) * 8;   // element offset within 64-wide row

    for (int k0 = 0; k0 < K; k0 += 64) {
#if HAS_GLL
        __syncthreads();  // all waves done reading previous LDS tiles
#pragma unroll
        for (int i = 0; i < 4; ++i) {
            int ch = wave * 4 + i;
            int row = ch * 8 + srow;
            __builtin_amdgcn_global_load_lds(AS1(Ag + (size_t)row * K + k0 + scol),
                                             AS3((char*)As + ch * 1024), 16, 0, 0);
            __builtin_amdgcn_global_load_lds(AS1(Bg + (size_t)row * K + k0 + scol),
                                             AS3((char*)Bs + ch * 1024), 16, 0, 0);
        }
        __syncthreads();  // compiler drains vmcnt before barrier
#else
        bf16x8 ta[4], tb[4];
#pragma unroll
        for (int i = 0; i < 4; ++i) {
            int ch = wave * 4 + i;
            int row = ch * 8 + srow;
            ta[i] = *(const bf16x8*)(Ag + (size_t)row * K + k0 + scol);
            tb[i] = *(const bf16x8*)(Bg + (size_t)row * K + k0 + scol);
        }
        __syncthreads();
#pragma unroll
        for (int i = 0; i < 4; ++i) {
            int ch = wave * 4 + i;
            *(bf16x8*)((char*)As + ch * 1024 + (size_t)lane * 16) = ta[i];
            *(bf16x8*)((char*)Bs + ch * 1024 + (size_t)lane * 16) = tb[i];
        }
        __syncthreads();
#endif
#pragma unroll
        for (int kk = 0; kk < 2; ++kk) {
            bf16x8 af[4], bfr[4];
#pragma unroll
            for (int mi = 0; mi < 4; ++mi)
                af[mi] = *(const bf16x8*)(As + (wm * 64 + mi * 16 + cc) * 64 + kk * 32 + g * 8);
#pragma unroll
            for (int ni = 0; ni < 4; ++ni)
                bfr[ni] = *(const bf16x8*)(Bs + (wn * 64 + ni * 16 + cc) * 64 + kk * 32 + g * 8);
#pragma unroll
            for (int mi = 0; mi < 4; ++mi)
#pragma unroll
                for (int ni = 0; ni < 4; ++ni)
                    acc[mi][ni] = __builtin_amdgcn_mfma_f32_16x16x32_bf16(
                        af[mi], bfr[ni], acc[mi][ni], 0, 0, 0);
        }
    }
    // epilogue: D[m = 4*(lane>>4)+r][n = lane&15] per 16x16 fragment
    int m0 = (bm << 7) + wm * 64;
    int n0 = (bn << 7) + wn * 64;
#pragma unroll
    for (int ni = 0; ni < 4; ++ni) {
        int n = n0 + ni * 16 + cc;
        float bv = bias[n];
#pragma unroll
        for (int mi = 0; mi < 4; ++mi) {
#pragma unroll
            for (int r = 0; r < 4; ++r) {
                int m = m0 + mi * 16 + g * 4 + r;
                float v = acc[mi][ni][r] + bv;
                if (EPI == 1) v = 0.5f * v * (1.f + erff(v * 0.70710678118654752f));
                if (EPI == 2)
                    ((float*)out)[(size_t)m * N + n] = res[(size_t)m * N + n] + v;
                else
                    ((bf16*)out)[(size_t)m * N + n] = (bf16)v;
            }
        }
    }
}

// ------------- flash attention: 4 waves x 16 q-rows, KV tiles of 32 --------
// Q/K/V addressed as ptr + ((b*Tdim + row)*rs) + h*hs ; out [B][T][512].
__global__ __launch_bounds__(256) void attn_kernel(
    const bf16* __restrict__ Qp, int q_rs, int q_hs,
    const bf16* __restrict__ Kp, int k_rs, int k_hs,
    const bf16* __restrict__ Vp, int v_rs, int v_hs,
    bf16* __restrict__ Op, int T_, int S_) {
    int numQ = T_ >> 6;
    int qb = blockIdx.x % numQ;
    int bh = blockIdx.x / numQ;
    int b = bh >> 3, h = bh & 7;
    int tid = threadIdx.x, wave = tid >> 6, lane = tid & 63;
    int g = lane >> 4, cc = lane & 15;
    int qrow0 = qb * 64 + wave * 16;

    const bf16* Qb = Qp + ((size_t)b * T_ + qrow0) * q_rs + h * q_hs;
    const bf16* Kb = Kp + ((size_t)b * S_) * k_rs + h * k_hs;
    const bf16* Vb = Vp + ((size_t)b * S_) * v_rs + h * v_hs;

    // Q fragments: A[m=lane&15][k=8*(lane>>4)+j], two k-halves of ch=64
    bf16x8 qf0 = *(const bf16x8*)(Qb + (size_t)cc * q_rs + g * 8);
    bf16x8 qf1 = *(const bf16x8*)(Qb + (size_t)cc * q_rs + 32 + g * 8);

    __shared__ __align__(16) bf16 Vt[64][40];      // V^T tile (pad stride 40 = 80B)
    __shared__ __align__(16) bf16 Pw[4][16][40];   // per-wave P tile

    float m_r[4], l_r[4];
    f32x4 o_acc[4] = {};
#pragma unroll
    for (int r = 0; r < 4; ++r) { m_r[r] = -1e30f; l_r[r] = 0.f; }

    for (int s0 = 0; s0 < S_; s0 += 32) {
        // issue V tile loads (coalesced uint pairs) early
        uint32_t vreg[4];
#pragma unroll
        for (int e = 0; e < 4; ++e) {
            int idx = tid + 256 * e;           // 0..1023
            int s = idx >> 5;                  // 0..31
            int cp = (idx & 31) * 2;           // 0..62
            vreg[e] = *(const uint32_t*)(Vb + (size_t)(s0 + s) * v_rs + cp);
        }
        // QK^T: two 16-col subtiles, K fragments direct from global (L2)
        f32x4 sf[2] = {};
#pragma unroll
        for (int sn = 0; sn < 2; ++sn) {
            bf16x8 kf0 = *(const bf16x8*)(Kb + (size_t)(s0 + sn * 16 + cc) * k_rs + g * 8);
            bf16x8 kf1 = *(const bf16x8*)(Kb + (size_t)(s0 + sn * 16 + cc) * k_rs + 32 + g * 8);
            sf[sn] = __builtin_amdgcn_mfma_f32_16x16x32_bf16(qf0, kf0, sf[sn], 0, 0, 0);
            sf[sn] = __builtin_amdgcn_mfma_f32_16x16x32_bf16(qf1, kf1, sf[sn], 0, 0, 0);
        }
        __syncthreads();  // everyone done with previous Vt
        // write V^T tile
#pragma unroll
        for (int e = 0; e < 4; ++e) {
            int idx = tid + 256 * e;
            int s = idx >> 5;
            int cp = (idx & 31) * 2;
            Vt[cp][s]     = us2bf((unsigned short)(vreg[e] & 0xffffu));
            Vt[cp + 1][s] = us2bf((unsigned short)(vreg[e] >> 16));
        }
        // online softmax; lane holds rows q=4g+r, cols sn*16+cc. scale=1/sqrt(64)
        float p0[4], p1[4], fsc[4];
#pragma unroll
        for (int r = 0; r < 4; ++r) {
            float s0v = sf[0][r] * 0.125f;
            float s1v = sf[1][r] * 0.125f;
            float pm = fmaxf(s0v, s1v);
            pm = fmaxf(pm, __shfl_xor(pm, 1));
            pm = fmaxf(pm, __shfl_xor(pm, 2));
            pm = fmaxf(pm, __shfl_xor(pm, 4));
            pm = fmaxf(pm, __shfl_xor(pm, 8));
            float mn = fmaxf(m_r[r], pm);
            fsc[r] = __expf(m_r[r] - mn);
            m_r[r] = mn;
            p0[r] = __expf(s0v - mn);
            p1[r] = __expf(s1v - mn);
            float q2 = p0[r] + p1[r];
            q2 += __shfl_xor(q2, 1);
            q2 += __shfl_xor(q2, 2);
            q2 += __shfl_xor(q2, 4);
            q2 += __shfl_xor(q2, 8);
            l_r[r] = l_r[r] * fsc[r] + q2;
        }
        // store P (bf16) for PV A-operand re-layout
#pragma unroll
        for (int r = 0; r < 4; ++r) {
            Pw[wave][4 * g + r][cc]      = (bf16)p0[r];
            Pw[wave][4 * g + r][16 + cc] = (bf16)p1[r];
        }
        __syncthreads();  // Vt ready; Pw writes drained (barrier waits lgkm)
        // PV: o = o*f + P[16x32] @ V[32x64]
        bf16x8 pa = *(const bf16x8*)(&Pw[wave][cc][g * 8]);
#pragma unroll
        for (int ni = 0; ni < 4; ++ni) {
            bf16x8 vf = *(const bf16x8*)(&Vt[ni * 16 + cc][g * 8]);
            f32x4 oo = o_acc[ni];
#pragma unroll
            for (int r = 0; r < 4; ++r) oo[r] *= fsc[r];
            o_acc[ni] = __builtin_amdgcn_mfma_f32_16x16x32_bf16(pa, vf, oo, 0, 0, 0);
        }
    }
    // epilogue: out[b][qrow0+4g+r][h*64 + ni*16 + cc]
#pragma unroll
    for (int r = 0; r < 4; ++r) {
        float inv = 1.f / l_r[r];
#pragma unroll
        for (int ni = 0; ni < 4; ++ni) {
            Op[((size_t)b * T_ + qrow0 + 4 * g + r) * 512 + h * 64 + ni * 16 + cc] =
                (bf16)(o_acc[ni][r] * inv);
        }
    }
}

// ---------------------------------------------------------------------------
extern "C" void kernel_launch(void* const* d_in, const int* in_sizes, int n_in,
                              void* d_out, int out_size, void* d_ws, size_t ws_size,
                              hipStream_t stream) {
    const float* x_in    = (const float*)d_in[0];
    const float* cond_k  = (const float*)d_in[1];
    const float* cond_v  = (const float*)d_in[2];
    const float* qkv_w   = (const float*)d_in[3];
    const float* qkv_b   = (const float*)d_in[4];
    const float* attn_w  = (const float*)d_in[5];
    const float* attn_b  = (const float*)d_in[6];
    const float* cross_w = (const float*)d_in[7];
    const float* cross_b = (const float*)d_in[8];
    const float* fc_w    = (const float*)d_in[9];
    const float* fc_b    = (const float*)d_in[10];
    const float* mlp_w   = (const float*)d_in[11];
    const float* mlp_b   = (const float*)d_in[12];
    const float* ln1_g   = (const float*)d_in[13];
    const float* ln1_b   = (const float*)d_in[14];
    const float* ln3_g   = (const float*)d_in[15];
    const float* ln3_b   = (const float*)d_in[16];
    const float* ln4_g   = (const float*)d_in[17];
    const float* ln4_b   = (const float*)d_in[18];

    const int L = 4, T = 2048, S = 512, W = 512;
    const int M = 2 * T;  // B*T rows

    char* ws = (char*)d_ws;
    size_t off = 0;
    auto carve = [&](size_t bytes) -> char* {
        char* p = ws + off;
        off += (bytes + 255) & ~(size_t)255;
        return p;
    };
    bf16* wqkv  = (bf16*)carve((size_t)L * 1536 * 512 * 2);
    bf16* wattn = (bf16*)carve((size_t)L * 512 * 512 * 2);
    bf16* wcrs  = (bf16*)carve((size_t)L * 512 * 512 * 2);
    bf16* wfc   = (bf16*)carve((size_t)L * 2048 * 512 * 2);
    bf16* wmlp  = (bf16*)carve((size_t)L * 512 * 2048 * 2);
    bf16* ckb   = (bf16*)carve((size_t)2 * S * W * 2);
    bf16* cvb   = (bf16*)carve((size_t)2 * S * W * 2);
    bf16* hbuf  = (bf16*)carve((size_t)M * 512 * 2);
    bf16* qkvb  = (bf16*)carve((size_t)M * 1536 * 2);
    bf16* abuf  = (bf16*)carve((size_t)M * 512 * 2);
    bf16* fcb   = (bf16*)carve((size_t)M * 2048 * 2);

    dim3 tb(32, 8);
    wtrans_kernel<<<dim3(1536 / 32, 512 / 32, L), tb, 0, stream>>>(qkv_w, wqkv, 512, 1536);
    wtrans_kernel<<<dim3(512 / 32, 512 / 32, L), tb, 0, stream>>>(attn_w, wattn, 512, 512);
    wtrans_kernel<<<dim3(512 / 32, 512 / 32, L), tb, 0, stream>>>(cross_w, wcrs, 512, 512);
    wtrans_kernel<<<dim3(2048 / 32, 512 / 32, L), tb, 0, stream>>>(fc_w, wfc, 512, 2048);
    wtrans_kernel<<<dim3(512 / 32, 2048 / 32, L), tb, 0, stream>>>(mlp_w, wmlp, 2048, 512);
    cvt_kernel<<<(2 * S * W) / 2048, 256, 0, stream>>>(cond_k, ckb, 2 * S * W);
    cvt_kernel<<<(2 * S * W) / 2048, 256, 0, stream>>>(cond_v, cvb, 2 * S * W);

    float* x = (float*)d_out;
    hipMemcpyAsync(x, (const void*)x_in, (size_t)M * W * sizeof(float),
                   hipMemcpyDeviceToDevice, stream);

    const int nAttnBlocks = 2 * 8 * (T / 64);  // 512
    for (int i = 0; i < L; ++i) {
        // self-attention sub-block
        ln_kernel<<<M / 4, 256, 0, stream>>>(x, ln1_g + i * 512, ln1_b + i * 512, hbuf);
        gemm_kernel<0><<<(M / 128) * (1536 / 128), 256, 0, stream>>>(
            hbuf, wqkv + (size_t)i * 1536 * 512, qkv_b + i * 1536, nullptr, qkvb,
            M, 1536, 512);
        attn_kernel<<<nAttnBlocks, 256, 0, stream>>>(
            qkvb, 1536, 192, qkvb + 64, 1536, 192, qkvb + 128, 1536, 192,
            abuf, T, T);
        gemm_kernel<2><<<(M / 128) * (512 / 128), 256, 0, stream>>>(
            abuf, wattn + (size_t)i * 512 * 512, attn_b + i * 512, x, x,
            M, 512, 512);
        // cross-attention sub-block
        ln_kernel<<<M / 4, 256, 0, stream>>>(x, ln3_g + i * 512, ln3_b + i * 512, hbuf);
        attn_kernel<<<nAttnBlocks, 256, 0, stream>>>(
            hbuf, 512, 64, ckb, 512, 64, cvb, 512, 64, abuf, T, S);
        gemm_kernel<2><<<(M / 128) * (512 / 128), 256, 0, stream>>>(
            abuf, wcrs + (size_t)i * 512 * 512, cross_b + i * 512, x, x,
            M, 512, 512);
        // MLP sub-block
        ln_kernel<<<M / 4, 256, 0, stream>>>(x, ln4_g + i * 512, ln4_b + i * 512, hbuf);
        gemm_kernel<1><<<(M / 128) * (2048 / 128), 256, 0, stream>>>(
            hbuf, wfc + (size_t)i * 2048 * 512, fc_b + i * 2048, nullptr, fcb,
            M, 2048, 512);
        gemm_kernel<2><<<(M / 128) * (512 / 128), 256, 0, stream>>>(
            fcb, wmlp + (size_t)i * 512 * 2048, mlp_b + i * 512, x, x,
            M, 512, 2048);
    }
}

// Round 2
// 835.474 us; speedup vs baseline: 1.4493x; 1.4493x over previous
//
#include <hip/hip_runtime.h>
#include <hip/hip_bf16.h>
#include <cstdint>

// ---------------------------------------------------------------------------
// Model: 4x [LN -> QKV -> self-attn -> proj+res -> LN -> cross-attn ->
//            proj+res -> LN -> FC+GELU -> proj+res]
// B=2 T=2048 S=512 W=512 H=8 ch=64, all matmuls bf16 MFMA 16x16x32, fp32 accum.
// ---------------------------------------------------------------------------

typedef __bf16 bf16;
typedef __bf16 bf16x8 __attribute__((ext_vector_type(8)));
typedef float f32x4 __attribute__((ext_vector_type(4)));

#define AS1(p) ((__attribute__((address_space(1))) void*)(uintptr_t)(p))
#define AS3(p) ((__attribute__((address_space(3))) void*)(p))

__device__ __forceinline__ bf16 us2bf(unsigned short u) {
    return __builtin_bit_cast(bf16, u);
}
__device__ __forceinline__ unsigned short bf2us(bf16 v) {
    return __builtin_bit_cast(unsigned short, v);
}

// ---------------- LayerNorm (f32 in) -> bf16 out, W=512 -------------------
__global__ __launch_bounds__(256) void ln_kernel(const float* __restrict__ x,
                                                 const float* __restrict__ gam,
                                                 const float* __restrict__ bet,
                                                 bf16* __restrict__ h) {
    int row  = blockIdx.x * 4 + (threadIdx.x >> 6);
    int lane = threadIdx.x & 63;
    const float4* xr = (const float4*)(x + (size_t)row * 512) + lane * 2;
    float4 a = xr[0], b = xr[1];
    float s  = a.x + a.y + a.z + a.w + b.x + b.y + b.z + b.w;
    float ss = a.x * a.x + a.y * a.y + a.z * a.z + a.w * a.w +
               b.x * b.x + b.y * b.y + b.z * b.z + b.w * b.w;
#pragma unroll
    for (int off = 1; off < 64; off <<= 1) {
        s  += __shfl_xor(s, off);
        ss += __shfl_xor(ss, off);
    }
    float mean = s * (1.f / 512.f);
    float var  = ss * (1.f / 512.f) - mean * mean;
    float rstd = rsqrtf(fmaxf(var, 0.f) + 1e-5f);
    const float4* gr = (const float4*)gam + lane * 2;
    const float4* br = (const float4*)bet + lane * 2;
    float4 g0 = gr[0], g1 = gr[1], b0 = br[0], b1 = br[1];
    bf16x8 hv;
    hv[0] = (bf16)((a.x - mean) * rstd * g0.x + b0.x);
    hv[1] = (bf16)((a.y - mean) * rstd * g0.y + b0.y);
    hv[2] = (bf16)((a.z - mean) * rstd * g0.z + b0.z);
    hv[3] = (bf16)((a.w - mean) * rstd * g0.w + b0.w);
    hv[4] = (bf16)((b.x - mean) * rstd * g1.x + b1.x);
    hv[5] = (bf16)((b.y - mean) * rstd * g1.y + b1.y);
    hv[6] = (bf16)((b.z - mean) * rstd * g1.z + b1.z);
    hv[7] = (bf16)((b.w - mean) * rstd * g1.w + b1.w);
    *(bf16x8*)(h + (size_t)row * 512 + lane * 8) = hv;
}

// ------------- transpose+convert: in f32 [L][K][N] -> out bf16 [L][N][K] ---
__global__ void wtrans_kernel(const float* __restrict__ in, bf16* __restrict__ out,
                              int K, int N) {
    __shared__ float tile[32][33];
    int n0 = blockIdx.x * 32, k0 = blockIdx.y * 32;
    const float* ip = in + (size_t)blockIdx.z * K * N;
    bf16* op = out + (size_t)blockIdx.z * N * K;
#pragma unroll
    for (int i = threadIdx.y; i < 32; i += 8)
        tile[i][threadIdx.x] = ip[(size_t)(k0 + i) * N + n0 + threadIdx.x];
    __syncthreads();
#pragma unroll
    for (int i = threadIdx.y; i < 32; i += 8)
        op[(size_t)(n0 + i) * K + k0 + threadIdx.x] = (bf16)tile[threadIdx.x][i];
}

// ------------- elementwise f32 -> bf16 ------------------------------------
__global__ void cvt_kernel(const float* __restrict__ in, bf16* __restrict__ out, int n) {
    int i = (blockIdx.x * 256 + threadIdx.x) * 8;
    if (i + 8 <= n) {
        const float4* p = (const float4*)(in + i);
        float4 a = p[0], b = p[1];
        bf16x8 v;
        v[0] = (bf16)a.x; v[1] = (bf16)a.y; v[2] = (bf16)a.z; v[3] = (bf16)a.w;
        v[4] = (bf16)b.x; v[5] = (bf16)b.y; v[6] = (bf16)b.z; v[7] = (bf16)b.w;
        *(bf16x8*)(out + i) = v;
    }
}

// ------------- GEMM: C = A[M][K] @ Bt[N][K]^T + bias, BM x 128 tile --------
// EPI 0: out bf16 = acc+bias
// EPI 1: out bf16 = gelu(acc+bias)
// EPI 2: out f32  = res + acc + bias     (res/out may alias: in-place x)
template <int EPI, int BM>
__global__ __launch_bounds__(256) void gemm_kernel(const bf16* __restrict__ A,
                                                   const bf16* __restrict__ Bt,
                                                   const float* __restrict__ bias,
                                                   const float* res, void* out,
                                                   int M, int N, int K) {
    constexpr int MI = BM / 32;  // acc rows per wave (4 for BM=128, 2 for BM=64)
    __shared__ __align__(16) bf16 As[BM * 64];
    __shared__ __align__(16) bf16 Bs[128 * 64];
    int tiles_n = N >> 7;
    int bid = blockIdx.x;
    int cpx = gridDim.x >> 3;           // grid % 8 == 0 for all our launches
    bid = (bid & 7) * cpx + (bid >> 3); // XCD-aware swizzle
    int bm = bid / tiles_n, bn = bid % tiles_n;
    int tid = threadIdx.x, wave = tid >> 6, lane = tid & 63;
    int wm = wave >> 1, wn = wave & 1;
    int g = lane >> 4, cc = lane & 15;
    f32x4 acc[MI][4] = {};
    const bf16* Ag = A + (size_t)(bm * BM) * K;
    const bf16* Bg = Bt + (size_t)(bn << 7) * K;
    int scol = (tid & 7) * 8;  // element offset within 64-wide row

    for (int k0 = 0; k0 < K; k0 += 64) {
        __syncthreads();  // all waves done reading previous LDS tiles
#pragma unroll
        for (int e = 0; e < BM / 32; ++e) {
            int row = (e * 256 + tid) >> 3;
            __builtin_amdgcn_global_load_lds(AS1(Ag + (size_t)row * K + k0 + scol),
                                             AS3((char*)As + e * 4096 + wave * 1024), 16, 0, 0);
        }
#pragma unroll
        for (int e = 0; e < 4; ++e) {
            int row = (e * 256 + tid) >> 3;
            __builtin_amdgcn_global_load_lds(AS1(Bg + (size_t)row * K + k0 + scol),
                                             AS3((char*)Bs + e * 4096 + wave * 1024), 16, 0, 0);
        }
        __syncthreads();  // compiler drains vmcnt before barrier
#pragma unroll
        for (int kk = 0; kk < 2; ++kk) {
            bf16x8 af[MI], bfr[4];
#pragma unroll
            for (int mi = 0; mi < MI; ++mi)
                af[mi] = *(const bf16x8*)(As + (wm * (BM / 2) + mi * 16 + cc) * 64 + kk * 32 + g * 8);
#pragma unroll
            for (int ni = 0; ni < 4; ++ni)
                bfr[ni] = *(const bf16x8*)(Bs + (wn * 64 + ni * 16 + cc) * 64 + kk * 32 + g * 8);
#pragma unroll
            for (int mi = 0; mi < MI; ++mi)
#pragma unroll
                for (int ni = 0; ni < 4; ++ni)
                    acc[mi][ni] = __builtin_amdgcn_mfma_f32_16x16x32_bf16(
                        af[mi], bfr[ni], acc[mi][ni], 0, 0, 0);
        }
    }
    // epilogue: D[m = 4*(lane>>4)+r][n = lane&15] per 16x16 fragment
    int m0 = bm * BM + wm * (BM / 2);
    int n0 = (bn << 7) + wn * 64;
#pragma unroll
    for (int ni = 0; ni < 4; ++ni) {
        int n = n0 + ni * 16 + cc;
        float bv = bias[n];
#pragma unroll
        for (int mi = 0; mi < MI; ++mi) {
#pragma unroll
            for (int r = 0; r < 4; ++r) {
                int m = m0 + mi * 16 + g * 4 + r;
                float v = acc[mi][ni][r] + bv;
                if (EPI == 1) v = 0.5f * v * (1.f + erff(v * 0.70710678118654752f));
                if (EPI == 2)
                    ((float*)out)[(size_t)m * N + n] = res[(size_t)m * N + n] + v;
                else
                    ((bf16*)out)[(size_t)m * N + n] = (bf16)v;
            }
        }
    }
}

// ------------- flash attention v2: swapped QK^T, KVBLK=64, 1 barrier/tile --
// Sv^T = K·Q^T (lane holds one q-row's P values) -> no-max softmax with
// per-lane scalar denominator -> P via per-wave swizzled LDS -> PV.
// All LDS tiles: rows of 128B, chunk XOR-swizzled by (row&7).
__global__ __launch_bounds__(256) void attn_kernel(
    const bf16* __restrict__ Qp, int q_rs, int q_hs,
    const bf16* __restrict__ Kp, int k_rs, int k_hs,
    const bf16* __restrict__ Vp, int v_rs, int v_hs,
    bf16* __restrict__ Op, int T_, int S_) {
    __shared__ __align__(16) char KB[2][8192];   // K tiles [64 s][64 ch] swizzled
    __shared__ __align__(16) char VT[2][8192];   // V^T tiles [64 ch][64 s] swizzled
    __shared__ __align__(16) char PB[4][2048];   // per-wave P [16 q][64 s] swizzled

    int numQ = T_ >> 6;
    int bid = blockIdx.x;
    int cpx = gridDim.x >> 3;            // grid = 512, %8==0
    bid = (bid & 7) * cpx + (bid >> 3);  // XCD swizzle: same (b,h) clusters per XCD
    int qb = bid % numQ;
    int bh = bid / numQ;
    int b = bh >> 3, h = bh & 7;
    int tid = threadIdx.x, wave = tid >> 6, lane = tid & 63;
    int g = lane >> 4, cc = lane & 15;
    int xr = cc & 7;
    int qrow0 = qb * 64 + wave * 16;

    const bf16* Qb = Qp + ((size_t)b * T_ + qrow0) * q_rs + h * q_hs;
    const bf16* Kb = Kp + ((size_t)b * S_) * k_rs + h * k_hs;
    const bf16* Vb = Vp + ((size_t)b * S_) * v_rs + h * v_hs;

    // Q fragments (B-operand): lane holds Q[q=cc][k=8g+j]; pre-scale by
    // (1/sqrt(ch)) * log2(e) so softmax is exp2(sf) directly.
    const float QSC = 0.125f * 1.44269504088896f;
    bf16x8 q0r = *(const bf16x8*)(Qb + (size_t)cc * q_rs + g * 8);
    bf16x8 q1r = *(const bf16x8*)(Qb + (size_t)cc * q_rs + 32 + g * 8);
    bf16x8 qf0, qf1;
#pragma unroll
    for (int j = 0; j < 8; ++j) {
        qf0[j] = (bf16)((float)q0r[j] * QSC);
        qf1[j] = (bf16)((float)q1r[j] * QSC);
    }

    uint32_t vreg[8];
    float l_part = 0.f;
    f32x4 o_acc[4] = {};
    char* Pw = PB[wave];

    // ---- staging helpers ----
    auto stageK = [&](int s0, int buf) {
        // K tile 64x64: lane L=e*256+tid: dest row=L>>3, chunk'=L&7 (linear);
        // pre-swizzled global source chunk = chunk' ^ (row&7).
#pragma unroll
        for (int e = 0; e < 2; ++e) {
            int L = e * 256 + tid;
            int row = L >> 3, cp = L & 7;
            int col = (cp ^ (row & 7)) * 8;
            __builtin_amdgcn_global_load_lds(AS1(Kb + (size_t)(s0 + row) * k_rs + col),
                                             AS3(KB[buf] + e * 4096 + wave * 1024), 16, 0, 0);
        }
    };
    auto loadV = [&](int s0) {
#pragma unroll
        for (int e = 0; e < 8; ++e) {
            int idx = e * 256 + tid;  // 0..2047
            int s = idx >> 5, cp = idx & 31;
            vreg[e] = *(const uint32_t*)(Vb + (size_t)(s0 + s) * v_rs + cp * 2);
        }
    };
    auto writeVT = [&](int buf) {
        // V^T: row=ch (128B), col=s; byte = ch*128 + ((s>>3 ^ (ch&7))<<4) + (s&7)*2
#pragma unroll
        for (int e = 0; e < 8; ++e) {
            int idx = e * 256 + tid;
            int s = idx >> 5, cp = idx & 31;
            int c0 = cp * 2, c1 = cp * 2 + 1;
            int sc = ((s >> 3) << 4), sb = (s & 7) * 2;
            *(bf16*)(VT[buf] + c0 * 128 + (sc ^ ((c0 & 7) << 4)) + sb) =
                us2bf((unsigned short)(vreg[e] & 0xffffu));
            *(bf16*)(VT[buf] + c1 * 128 + (sc ^ ((c1 & 7) << 4)) + sb) =
                us2bf((unsigned short)(vreg[e] >> 16));
        }
    };

    // ---- prologue: tile 0 ----
    stageK(0, 0);
    loadV(0);
    __syncthreads();   // K0 in LDS (vmcnt drained at barrier)
    writeVT(0);
    __syncthreads();   // VT0 visible

    int nt = S_ >> 6;
    int cur = 0;
    for (int t = 0; t < nt; ++t) {
        bool pre = (t + 1 < nt);
        if (pre) { stageK((t + 1) * 64, cur ^ 1); loadV((t + 1) * 64); }
        // QK^T (swapped): sf[sn] = S^T[s = sn*16+4g+r][q = cc]
        f32x4 sf[4] = {};
#pragma unroll
        for (int kk = 0; kk < 2; ++kk) {
            int co = ((kk * 4 + g) ^ xr) << 4;
#pragma unroll
            for (int sn = 0; sn < 4; ++sn) {
                bf16x8 kf = *(const bf16x8*)(KB[cur] + (sn * 16 + cc) * 128 + co);
                sf[sn] = __builtin_amdgcn_mfma_f32_16x16x32_bf16(
                    kf, kk ? qf1 : qf0, sf[sn], 0, 0, 0);
            }
        }
        // no-max softmax: p = exp2(sf); per-lane scalar denominator (q = cc)
#pragma unroll
        for (int sn = 0; sn < 4; ++sn) {
            float p0 = exp2f(sf[sn][0]), p1 = exp2f(sf[sn][1]);
            float p2 = exp2f(sf[sn][2]), p3 = exp2f(sf[sn][3]);
            l_part += (p0 + p1) + (p2 + p3);
            uint32_t u01 = (uint32_t)bf2us((bf16)p0) | ((uint32_t)bf2us((bf16)p1) << 16);
            uint32_t u23 = (uint32_t)bf2us((bf16)p2) | ((uint32_t)bf2us((bf16)p3) << 16);
            // store P[q=cc][s=sn*16+4g+{0..3}] as one u64 (chunk = 2sn+(g>>1))
            int chunk = 2 * sn + (g >> 1);
            char* pb = Pw + cc * 128 + ((chunk ^ xr) << 4) + (g & 1) * 8;
            uint2 uu; uu.x = u01; uu.y = u23;
            *(uint2*)pb = uu;
        }
        // PV: o[q][ch] += P[q][s] * V[s][ch]
#pragma unroll
        for (int kk = 0; kk < 2; ++kk) {
            int co = ((kk * 4 + g) ^ xr) << 4;
            bf16x8 pa = *(const bf16x8*)(Pw + cc * 128 + co);
#pragma unroll
            for (int ni = 0; ni < 4; ++ni) {
                bf16x8 vf = *(const bf16x8*)(VT[cur] + (ni * 16 + cc) * 128 + co);
                o_acc[ni] = __builtin_amdgcn_mfma_f32_16x16x32_bf16(pa, vf, o_acc[ni], 0, 0, 0);
            }
        }
        if (pre) writeVT(cur ^ 1);  // safe: VT[cur^1] readers finished at t-1 barrier
        __syncthreads();            // release K/V writes for t+1
        cur ^= 1;
    }

    // denominator: reduce partials across the 4 g-groups (q = cc is full after)
    l_part += __shfl_xor(l_part, 16);
    l_part += __shfl_xor(l_part, 32);
    // epilogue: out[b][qrow0+4g+r][h*64 + ni*16 + cc]
#pragma unroll
    for (int r = 0; r < 4; ++r) {
        float lq = __shfl(l_part, 4 * g + r);  // lane (g'=0, cc=4g+r) holds l(q=4g+r)
        float inv = 1.f / lq;
#pragma unroll
        for (int ni = 0; ni < 4; ++ni) {
            Op[((size_t)b * T_ + qrow0 + 4 * g + r) * 512 + h * 64 + ni * 16 + cc] =
                (bf16)(o_acc[ni][r] * inv);
        }
    }
}

// ---------------------------------------------------------------------------
extern "C" void kernel_launch(void* const* d_in, const int* in_sizes, int n_in,
                              void* d_out, int out_size, void* d_ws, size_t ws_size,
                              hipStream_t stream) {
    const float* x_in    = (const float*)d_in[0];
    const float* cond_k  = (const float*)d_in[1];
    const float* cond_v  = (const float*)d_in[2];
    const float* qkv_w   = (const float*)d_in[3];
    const float* qkv_b   = (const float*)d_in[4];
    const float* attn_w  = (const float*)d_in[5];
    const float* attn_b  = (const float*)d_in[6];
    const float* cross_w = (const float*)d_in[7];
    const float* cross_b = (const float*)d_in[8];
    const float* fc_w    = (const float*)d_in[9];
    const float* fc_b    = (const float*)d_in[10];
    const float* mlp_w   = (const float*)d_in[11];
    const float* mlp_b   = (const float*)d_in[12];
    const float* ln1_g   = (const float*)d_in[13];
    const float* ln1_b   = (const float*)d_in[14];
    const float* ln3_g   = (const float*)d_in[15];
    const float* ln3_b   = (const float*)d_in[16];
    const float* ln4_g   = (const float*)d_in[17];
    const float* ln4_b   = (const float*)d_in[18];

    const int L = 4, T = 2048, S = 512, W = 512;
    const int M = 2 * T;  // B*T rows

    char* ws = (char*)d_ws;
    size_t off = 0;
    auto carve = [&](size_t bytes) -> char* {
        char* p = ws + off;
        off += (bytes + 255) & ~(size_t)255;
        return p;
    };
    bf16* wqkv  = (bf16*)carve((size_t)L * 1536 * 512 * 2);
    bf16* wattn = (bf16*)carve((size_t)L * 512 * 512 * 2);
    bf16* wcrs  = (bf16*)carve((size_t)L * 512 * 512 * 2);
    bf16* wfc   = (bf16*)carve((size_t)L * 2048 * 512 * 2);
    bf16* wmlp  = (bf16*)carve((size_t)L * 512 * 2048 * 2);
    bf16* ckb   = (bf16*)carve((size_t)2 * S * W * 2);
    bf16* cvb   = (bf16*)carve((size_t)2 * S * W * 2);
    bf16* hbuf  = (bf16*)carve((size_t)M * 512 * 2);
    bf16* qkvb  = (bf16*)carve((size_t)M * 1536 * 2);
    bf16* abuf  = (bf16*)carve((size_t)M * 512 * 2);
    bf16* fcb   = (bf16*)carve((size_t)M * 2048 * 2);

    dim3 tb(32, 8);
    wtrans_kernel<<<dim3(1536 / 32, 512 / 32, L), tb, 0, stream>>>(qkv_w, wqkv, 512, 1536);
    wtrans_kernel<<<dim3(512 / 32, 512 / 32, L), tb, 0, stream>>>(attn_w, wattn, 512, 512);
    wtrans_kernel<<<dim3(512 / 32, 512 / 32, L), tb, 0, stream>>>(cross_w, wcrs, 512, 512);
    wtrans_kernel<<<dim3(2048 / 32, 512 / 32, L), tb, 0, stream>>>(fc_w, wfc, 512, 2048);
    wtrans_kernel<<<dim3(512 / 32, 2048 / 32, L), tb, 0, stream>>>(mlp_w, wmlp, 2048, 512);
    cvt_kernel<<<(2 * S * W) / 2048, 256, 0, stream>>>(cond_k, ckb, 2 * S * W);
    cvt_kernel<<<(2 * S * W) / 2048, 256, 0, stream>>>(cond_v, cvb, 2 * S * W);

    float* x = (float*)d_out;
    hipMemcpyAsync(x, (const void*)x_in, (size_t)M * W * sizeof(float),
                   hipMemcpyDeviceToDevice, stream);

    const int nAttnBlocks = 2 * 8 * (T / 64);  // 512
    for (int i = 0; i < L; ++i) {
        // self-attention sub-block
        ln_kernel<<<M / 4, 256, 0, stream>>>(x, ln1_g + i * 512, ln1_b + i * 512, hbuf);
        gemm_kernel<0, 128><<<(M / 128) * (1536 / 128), 256, 0, stream>>>(
            hbuf, wqkv + (size_t)i * 1536 * 512, qkv_b + i * 1536, nullptr, qkvb,
            M, 1536, 512);
        attn_kernel<<<nAttnBlocks, 256, 0, stream>>>(
            qkvb, 1536, 192, qkvb + 64, 1536, 192, qkvb + 128, 1536, 192,
            abuf, T, T);
        gemm_kernel<2, 64><<<(M / 64) * (512 / 128), 256, 0, stream>>>(
            abuf, wattn + (size_t)i * 512 * 512, attn_b + i * 512, x, x,
            M, 512, 512);
        // cross-attention sub-block
        ln_kernel<<<M / 4, 256, 0, stream>>>(x, ln3_g + i * 512, ln3_b + i * 512, hbuf);
        attn_kernel<<<nAttnBlocks, 256, 0, stream>>>(
            hbuf, 512, 64, ckb, 512, 64, cvb, 512, 64, abuf, T, S);
        gemm_kernel<2, 64><<<(M / 64) * (512 / 128), 256, 0, stream>>>(
            abuf, wcrs + (size_t)i * 512 * 512, cross_b + i * 512, x, x,
            M, 512, 512);
        // MLP sub-block
        ln_kernel<<<M / 4, 256, 0, stream>>>(x, ln4_g + i * 512, ln4_b + i * 512, hbuf);
        gemm_kernel<1, 128><<<(M / 128) * (2048 / 128), 256, 0, stream>>>(
            hbuf, wfc + (size_t)i * 2048 * 512, fc_b + i * 2048, nullptr, fcb,
            M, 2048, 512);
        gemm_kernel<2, 64><<<(M / 64) * (512 / 128), 256, 0, stream>>>(
            fcb, wmlp + (size_t)i * 512 * 2048, mlp_b + i * 512, x, x,
            M, 512, 2048);
    }
}